// Round 1
// baseline (249.387 us; speedup 1.0000x reference)
//
#include <hip/hip_runtime.h>

#define HH 128
#define WW 128
#define CC 64
#define NPT 8     // points per thread
#define BS 1024   // threads per block (one block = one image row)

__global__ __launch_bounds__(BS) void diffusion_fused(
    const float* __restrict__ s0,
    const float* __restrict__ kg,  const float* __restrict__ kg1,
    const float* __restrict__ kDx, const float* __restrict__ kDy,
    const float* __restrict__ bng,  const float* __restrict__ bng1,
    const float* __restrict__ bnDx, const float* __restrict__ bnDy,
    const float* __restrict__ bn_out,
    float* __restrict__ out)
{
    __shared__ float Lg[WW * CC];   // 32 KB: g row (for W-axis neighbors of g)
    __shared__ float Lh[WW * CC];   // 32 KB: h row (for W-axis neighbors of h)

    const int t    = threadIdx.x;
    const int c    = t & 63;        // lane == channel
    const int wgrp = t >> 6;        // 0..15
    const int lane = t & 63;
    const int lm   = (lane + 63) & 63;   // channel c-1 (wrap)
    const int lp   = (lane + 1)  & 63;   // channel c+1 (wrap)
    const int bh   = blockIdx.x;         // b*128 + h
    const int hrow = bh & (HH - 1);
    const int rowbase = bh * (WW * CC);

    const float DTc = 0.2f;

    // ---- fold BN params for this channel: y = s*x + b ----
    float sg, bgc, sg1, bg1c, sdx, bdxc, sdy, bdyc, so, boc;
    {
        #define BNF(P, S, B) { float ga=P[c], be=P[64+c], mu=P[128+c], va=P[192+c]; \
                               S = ga * rsqrtf(va + 1e-3f); B = be - mu * S; }
        BNF(bng,    sg,  bgc);
        BNF(bng1,   sg1, bg1c);
        BNF(bnDx,   sdx, bdxc);
        BNF(bnDy,   sdy, bdyc);
        BNF(bn_out, so,  boc);
        #undef BNF
    }

    // ---- depthwise conv taps for this channel ----
    float wgt_g[9], wgt_g1[9], wgt_dx[9], wgt_dy[9];
    #pragma unroll
    for (int k = 0; k < 9; ++k) {
        wgt_g[k]  = kg [k * CC + c];
        wgt_g1[k] = kg1[k * CC + c];
        wgt_dx[k] = kDx[k * CC + c];
        wgt_dy[k] = kDy[k * CC + c];
    }

    float garr[NPT], g1arr[NPT], bxarr[NPT], byarr[NPT], farr[NPT];

    // ---- phase 1a: 3x3 depthwise convs (SAME, zero pad) + BN + ReLU ----
    #pragma unroll
    for (int i = 0; i < NPT; ++i) {
        const int w = i * 16 + wgrp;
        float ag = 0.f, ag1 = 0.f, adx = 0.f, ady = 0.f, fc = 0.f;
        #pragma unroll
        for (int dh = -1; dh <= 1; ++dh) {
            const int h2 = hrow + dh;
            if (h2 < 0 || h2 >= HH) continue;           // block-uniform branch
            const float* rp = s0 + rowbase + dh * (WW * CC);
            #pragma unroll
            for (int dw = -1; dw <= 1; ++dw) {
                const int w2 = w + dw;
                if (w2 < 0 || w2 >= WW) continue;       // wave-uniform branch
                const float v = rp[w2 * CC + c];
                const int k = (dh + 1) * 3 + (dw + 1);
                ag  = fmaf(v, wgt_g[k],  ag);
                ag1 = fmaf(v, wgt_g1[k], ag1);
                adx = fmaf(v, wgt_dx[k], adx);
                ady = fmaf(v, wgt_dy[k], ady);
                if (dh == 0 && dw == 0) fc = v;
            }
        }
        const float g  = fmaxf(fmaf(ag,  sg,  bgc ), 0.f);
        const float g1 = fmaxf(fmaf(ag1, sg1, bg1c), 0.f);
        garr[i]  = g;
        g1arr[i] = g1;
        bxarr[i] = fmaxf(fmaf(adx, sdx, bdxc), 0.f) * DTc;   // Bx = Dx*dt
        byarr[i] = fmaxf(fmaf(ady, sdy, bdyc), 0.f) * DTc;   // By = Dy*dt
        farr[i]  = fc;
        Lg[w * CC + c] = g;
        Lh[w * CC + c] = fc;   // h starts as f
    }
    __syncthreads();

    // ---- phase 1b: loop-invariant PDE coefficients (h0 == f for K=2) ----
    float A0[NPT], cE[NPT], cWm[NPT], cWp[NPT], cCm[NPT], cCp[NPT], hreg[NPT];
    #pragma unroll
    for (int i = 0; i < NPT; ++i) {
        const int w  = i * 16 + wgrp;
        const int wm = ((w + WW - 1) & (WW - 1)) * CC + c;
        const int wp = ((w + 1)      & (WW - 1)) * CC + c;
        // ux[w] = 0.5*(g[w-1] - g[w+1]) wrap; vy[c] = 0.5*(g1[c-1] - g1[c+1]) wrap
        const float ux  = 0.5f * (Lg[wm] - Lg[wp]);
        const float g1m = __shfl(g1arr[i], lm);
        const float g1p = __shfl(g1arr[i], lp);
        const float vy  = 0.5f * (g1m - g1p);
        const float E   = (ux + vy) * DTc;
        const float bx  = bxarr[i], by = byarr[i];
        const float D   = 1.0f / (1.0f + 2.f * bx + 2.f * by);
        const float Ax  = garr[i]  * DTc;
        const float Ay  = g1arr[i] * DTc;
        A0[i]  = D * farr[i] * (1.f - 2.f * bx - 2.f * by + 2.f * DTc);
        cE[i]  = -2.f * E * D;
        cWm[i] = D * (2.f * bx - Ax);   // coeff of h[w-1]
        cWp[i] = D * (2.f * bx + Ax);   // coeff of h[w+1]
        cCm[i] = D * (2.f * by - Ay);   // coeff of h[c-1]
        cCp[i] = D * (2.f * by + Ay);   // coeff of h[c+1]
        hreg[i] = farr[i];
    }

    // ---- PDE: K=2 steps ----
    #pragma unroll
    for (int it = 0; it < 2; ++it) {
        float hn[NPT];
        #pragma unroll
        for (int i = 0; i < NPT; ++i) {
            const int w  = i * 16 + wgrp;
            const int wm = ((w + WW - 1) & (WW - 1)) * CC + c;
            const int wp = ((w + 1)      & (WW - 1)) * CC + c;
            const float hmc = __shfl(hreg[i], lm);   // h[w, c-1]
            const float hpc = __shfl(hreg[i], lp);   // h[w, c+1]
            hn[i] = A0[i]
                  + cE[i]  * hreg[i]
                  + cWm[i] * Lh[wm]
                  + cWp[i] * Lh[wp]
                  + cCm[i] * hmc
                  + cCp[i] * hpc;
        }
        __syncthreads();   // all Lh reads done
        #pragma unroll
        for (int i = 0; i < NPT; ++i) {
            const int w = i * 16 + wgrp;
            Lh[w * CC + c] = hn[i];
            hreg[i] = hn[i];
        }
        __syncthreads();   // writes visible
    }

    // ---- epilogue: BN + ReLU ----
    #pragma unroll
    for (int i = 0; i < NPT; ++i) {
        const int w = i * 16 + wgrp;
        out[rowbase + w * CC + c] = fmaxf(fmaf(hreg[i], so, boc), 0.f);
    }
}

extern "C" void kernel_launch(void* const* d_in, const int* in_sizes, int n_in,
                              void* d_out, int out_size, void* d_ws, size_t ws_size,
                              hipStream_t stream) {
    const float* s0   = (const float*)d_in[0];
    const float* kg   = (const float*)d_in[1];
    const float* kg1  = (const float*)d_in[2];
    const float* kDx  = (const float*)d_in[3];
    const float* kDy  = (const float*)d_in[4];
    const float* bng  = (const float*)d_in[5];
    const float* bng1 = (const float*)d_in[6];
    const float* bnDx = (const float*)d_in[7];
    const float* bnDy = (const float*)d_in[8];
    const float* bno  = (const float*)d_in[9];
    float* out = (float*)d_out;

    dim3 grid(16 * 128);   // one block per (batch, row)
    dim3 block(BS);
    diffusion_fused<<<grid, block, 0, stream>>>(
        s0, kg, kg1, kDx, kDy, bng, bng1, bnDx, bnDy, bno, out);
}